// Round 10
// baseline (487.951 us; speedup 1.0000x reference)
//
#include <hip/hip_runtime.h>
#include <math.h>

// TreeLSTM MI355X — R22: revert lvl7 tail "fix"; fuse lvl5..0 into tree_tail.
// R21 post-mortem (449us): ht_mfma fusion + lvl8_cell/leaf_rep fold won, but
// lvl7 cbN=2 regressed 70.6->76 (FETCH 39.8->58.5MB: double A-staging cost >
// tail gain) -> reverted to proven cbN=4. Remaining spread: six tiny lvl5..0
// launches (grids 1024->32 blocks) pay launch+tail+global h/c round-trips
// (~130KB/tree re-read). R22 tree_tail: 1 block per tree walks lvl5->0 with
// h (A-frag layout) + c in LDS ping-pong (113KB), B streamed per level from
// L2-resident Wfrag via the proven 2-barrier kc schedule; rep for nodes 0..62
// accumulated in LDS, one atomicAdd per (tree,col). rep_accum(hUpLow) now
// scans nodes 63..254 only. Memory layout unchanged (233.18 MB).

typedef _Float16 h16;
typedef h16 f16x8 __attribute__((ext_vector_type(8)));
typedef h16 h16x4 __attribute__((ext_vector_type(4)));
typedef float f32x4 __attribute__((ext_vector_type(4)));

#define HS 256
#define NTREE 1023
#define B2 256

#define DMA16(gp, lp) __builtin_amdgcn_global_load_lds( \
    (const __attribute__((address_space(1))) void*)(gp), \
    (__attribute__((address_space(3))) void*)(lp), 16, 0, 0)

__device__ __forceinline__ float sigf(float x){
  return __builtin_amdgcn_rcpf(1.0f + exp2f(x * -1.44269504f));
}
// sigmoid(a)*tanh(b) in 3 trans (exp2,exp2,rcp). Clamp avoids E2=inf -> NaN.
__device__ __forceinline__ float sig_mul_tanh(float a, float b){
  const float E1 = exp2f(a * -1.44269504f);
  const float E2 = exp2f(fminf(b * -2.88539008f, 126.0f));
  return (1.0f - E2) * __builtin_amdgcn_rcpf((1.0f + E1) * (1.0f + E2));
}

// ------------- convert fp32 -> fp16 (emb, Ufw, Uiou, Wiou) + zero rep -------
__global__ __launch_bounds__(256) void convert_all(const float* __restrict__ emb,
    const float* __restrict__ Ufw, const float* __restrict__ Uiou,
    const float* __restrict__ Wiou, h16* __restrict__ emb16,
    h16* __restrict__ W16, h16* __restrict__ Wx16, float* __restrict__ rep){
  if (blockIdx.x < 64)
    ((float4*)rep)[blockIdx.x*256 + threadIdx.x] = make_float4(0.f,0.f,0.f,0.f);
  const size_t i0 = ((size_t)blockIdx.x*256 + threadIdx.x)*8;
  const float* src; h16* dst; size_t off;
  if (i0 < 8192000UL){ src = emb;  dst = emb16;       off = i0; }
  else if (i0 < 8257536UL){ src = Ufw;  dst = W16;        off = i0 - 8192000UL; }
  else if (i0 < 8454144UL){ src = Uiou; dst = W16+65536;  off = i0 - 8257536UL; }
  else               { src = Wiou; dst = Wx16;       off = i0 - 8454144UL; }
  const float4 v0 = *(const float4*)&src[off];
  const float4 v1 = *(const float4*)&src[off+4];
  f16x8 o;
  o[0]=(h16)v0.x; o[1]=(h16)v0.y; o[2]=(h16)v0.z; o[3]=(h16)v0.w;
  o[4]=(h16)v1.x; o[5]=(h16)v1.y; o[6]=(h16)v1.z; o[7]=(h16)v1.w;
  *(f16x8*)&dst[off] = o;
}

// ------------- swizzle W16 -> Wfrag (4 gates) and Wx16 -> WxFrag (3 gates) --
__global__ __launch_bounds__(256) void swizzle_all(const h16* __restrict__ W16,
    const h16* __restrict__ Wx16, h16* __restrict__ Wfrag,
    h16* __restrict__ WxFrag){
  const int tid = blockIdx.x*256 + threadIdx.x;   // 0..90111
  if (tid < 65536){
    const int lane = tid & 63;
    const int f    = (tid >> 6) & 15;
    const int kc   = (tid >> 10) & 7;
    const int cb   = tid >> 13;
    const int g = f >> 2, cf = f & 3;
    const int row = g*256 + cb*64 + cf*16 + (lane & 15);
    const int col = kc*32 + (lane >> 4)*8;
    const f16x8 v = *(const f16x8*)&W16[(size_t)row*256 + col];
    *(f16x8*)&Wfrag[(size_t)tid*8] = v;
  } else {
    const int t2 = tid - 65536;          // 0..24575
    const int lane = t2 & 63;
    const int frag = t2 >> 6;            // 0..383 = cb*96 + kc*12 + f
    const int cb  = frag / 96;
    const int rem = frag % 96;
    const int kc  = rem / 12;
    const int f   = rem % 12;
    const int g = f >> 2, cf = f & 3;    // g in {0,1,2} = i,o,u
    const int row = g*256 + cb*64 + cf*16 + (lane & 15);
    const int col = kc*32 + (lane >> 4)*8;
    const f16x8 v = *(const f16x8*)&Wx16[(size_t)row*256 + col];
    *(f16x8*)&WxFrag[(size_t)frag*512 + lane*8] = v;
  }
}

// ------------- hT,cT = leaf cell(emb @ Wx^T + b) per TYPE (fused) -----------
__global__ __launch_bounds__(256,3) void ht_mfma(const h16* __restrict__ emb16,
    const h16* __restrict__ WxFrag, const float* __restrict__ biou,
    h16* __restrict__ hT, h16* __restrict__ cT){
  __shared__ h16 ldsA[4*8*64*8];   // 32 KB
  __shared__ h16 ldsB[12*64*8];    // 12 KB
  const int t = threadIdx.x, w = t >> 6, l = t & 63;
  const int q = l >> 4, li = l & 15;
  const int waveR = w & 1, waveC = w >> 1;
  const int bx = blockIdx.x;

  {
    const int grow = bx*64 + w*16 + li;
    const size_t abase = (size_t)grow * 256;
    #pragma unroll
    for (int kc=0; kc<8; ++kc)
      DMA16(emb16 + abase + kc*32 + q*8, &ldsA[(w*8 + kc)*512]);
  }

  for (int cb=0; cb<4; ++cb){
    const h16* wfBase = WxFrag + (size_t)cb*8*12*512 + (size_t)l*8;

    #pragma unroll
    for (int i=0; i<3; ++i)
      DMA16(wfBase + ((size_t)(w*3 + i))*512, &ldsB[(w*3 + i)*512]);
    __syncthreads();   // drains A (cb0) + B(0)

    f32x4 acc[3][2][2] = {};   // [gate i,o,u][rt][ct]
    #pragma unroll
    for (int kc=0; kc<8; ++kc){
      f16x8 aF[2], bF[3][2];
      #pragma unroll
      for (int rt=0; rt<2; ++rt)
        aF[rt] = *(const f16x8*)&ldsA[(((waveR*2 + rt)*8 + kc)*64 + l)*8];
      #pragma unroll
      for (int g=0; g<3; ++g)
        #pragma unroll
        for (int ct=0; ct<2; ++ct)
          bF[g][ct] = *(const f16x8*)&ldsB[((g*4 + waveC*2 + ct)*64 + l)*8];
      __syncthreads();   // reads done
      if (kc < 7){
        #pragma unroll
        for (int i=0; i<3; ++i)
          DMA16(wfBase + ((size_t)(kc+1)*12 + w*3 + i)*512,
                &ldsB[(w*3 + i)*512]);
      }
      #pragma unroll
      for (int g=0; g<3; ++g)
        #pragma unroll
        for (int rt=0; rt<2; ++rt)
          #pragma unroll
          for (int ct=0; ct<2; ++ct)
            acc[g][rt][ct] = __builtin_amdgcn_mfma_f32_16x16x32_f16(
                aF[rt], bF[g][ct], acc[g][rt][ct], 0,0,0);
      __syncthreads();   // drains B(kc+1)
    }

    // epilogue: leaf cell from f32 pre-acts, write hT/cT
    #pragma unroll
    for (int ct=0; ct<2; ++ct){
      const int c = cb*64 + waveC*32 + ct*16 + li;
      const float bi = biou[c], bo = biou[256+c], bu = biou[512+c];
      #pragma unroll
      for (int rt=0; rt<2; ++rt){
        #pragma unroll
        for (int reg=0; reg<4; ++reg){
          const int row = bx*64 + waveR*32 + rt*16 + q*4 + reg;
          const float iv = acc[0][rt][ct][reg] + bi;
          const float ov = acc[1][rt][ct][reg] + bo;
          const float uv = acc[2][rt][ct][reg] + bu;
          const float cc = sig_mul_tanh(iv, uv);
          const float hh = sig_mul_tanh(ov, cc);
          hT[(size_t)row*256 + c] = (h16)hh;
          cT[(size_t)row*256 + c] = (h16)cc;
        }
      }
    }
  }
}

// ------------- GT16 = [Ufw;Uiou] @ hT^T per type, h16x4 interleaved ---------
__global__ __launch_bounds__(256,3) void gt16_mfma(const h16* __restrict__ hT,
    const h16* __restrict__ Wfrag, const float* __restrict__ biou,
    const float* __restrict__ Ufb, h16* __restrict__ GT16){
  __shared__ h16 ldsA[4*8*64*8];   // 32 KB
  __shared__ h16 ldsB[16*64*8];    // 16 KB
  const int t = threadIdx.x, w = t >> 6, l = t & 63;
  const int q = l >> 4, li = l & 15;
  const int waveR = w & 1, waveC = w >> 1;
  const int bx = blockIdx.x;

  {
    const int grow = bx*64 + w*16 + li;
    const size_t abase = (size_t)grow * 256;
    #pragma unroll
    for (int kc=0; kc<8; ++kc)
      DMA16(hT + abase + kc*32 + q*8, &ldsA[(w*8 + kc)*512]);
  }

  for (int cb=0; cb<4; ++cb){
    const h16* wfBase = Wfrag + (size_t)cb*8*16*512 + (size_t)l*8;

    #pragma unroll
    for (int i=0; i<4; ++i)
      DMA16(wfBase + ((size_t)(w*4 + i))*512, &ldsB[(w*4 + i)*512]);
    __syncthreads();

    f32x4 acc[4][2][2] = {};
    #pragma unroll
    for (int kc=0; kc<8; ++kc){
      f16x8 aF[2], bF[4][2];
      #pragma unroll
      for (int rt=0; rt<2; ++rt)
        aF[rt] = *(const f16x8*)&ldsA[(((waveR*2 + rt)*8 + kc)*64 + l)*8];
      #pragma unroll
      for (int g=0; g<4; ++g)
        #pragma unroll
        for (int ct=0; ct<2; ++ct)
          bF[g][ct] = *(const f16x8*)&ldsB[((g*4 + waveC*2 + ct)*64 + l)*8];
      __syncthreads();
      if (kc < 7){
        #pragma unroll
        for (int i=0; i<4; ++i)
          DMA16(wfBase + ((size_t)(kc+1)*16 + w*4 + i)*512,
                &ldsB[(w*4 + i)*512]);
      }
      #pragma unroll
      for (int g=0; g<4; ++g)
        #pragma unroll
        for (int rt=0; rt<2; ++rt)
          #pragma unroll
          for (int ct=0; ct<2; ++ct)
            acc[g][rt][ct] = __builtin_amdgcn_mfma_f32_16x16x32_f16(
                aF[rt], bF[g][ct], acc[g][rt][ct], 0,0,0);
      __syncthreads();
    }

    #pragma unroll
    for (int ct=0; ct<2; ++ct){
      const int c = cb*64 + waveC*32 + ct*16 + li;
      const float fb  = Ufb[c];
      const float bi2 = 0.5f*biou[c], bo2 = 0.5f*biou[256+c], bu2 = 0.5f*biou[512+c];
      #pragma unroll
      for (int rt=0; rt<2; ++rt){
        #pragma unroll
        for (int reg=0; reg<4; ++reg){
          const int row = bx*64 + waveR*32 + rt*16 + q*4 + reg;
          h16x4 o;
          o[0] = (h16)(acc[0][rt][ct][reg] + fb);
          o[1] = (h16)(acc[1][rt][ct][reg] + bi2);
          o[2] = (h16)(acc[2][rt][ct][reg] + bo2);
          o[3] = (h16)(acc[3][rt][ct][reg] + bu2);
          *(h16x4*)&GT16[(size_t)row*1024 + c*4] = o;
        }
      }
    }
  }
}

// ------------- lvl8: gather+cell + leaf-rep fold (no MFMA/LDS/barriers) -----
__global__ __launch_bounds__(256) void lvl8_cell(const int* __restrict__ t1,
    const int* __restrict__ t2, const h16* __restrict__ GT16,
    const h16* __restrict__ cT, const h16* __restrict__ hT,
    h16* __restrict__ hUpHigh, h16* __restrict__ cPar,
    float* __restrict__ rep){
  const int k = threadIdx.x;
  const int m0 = blockIdx.x*32;
  const int rr = m0 >> 8;
  const int* tp = (rr < 128) ? t1 : t2;
  const int b = rr & 127;
  float s = 0.f;
  #pragma unroll 4
  for (int p=0; p<32; ++p){
    const int m = m0 + p, jn = m & 255;
    const size_t vl = (size_t)tp[b*NTREE + 511 + 2*jn];
    const size_t vr = (size_t)tp[b*NTREE + 512 + 2*jn];
    const h16x4 gl = *(const h16x4*)&GT16[vl*1024 + k*4];
    const h16x4 gr = *(const h16x4*)&GT16[vr*1024 + k*4];
    const float cl = (float)cT[vl*256 + k];
    const float cr = (float)cT[vr*256 + k];
    const float fl = sigf((float)gl[0]);
    const float fr = sigf((float)gr[0]);
    const float iv = (float)gl[1] + (float)gr[1];
    const float ov = (float)gl[2] + (float)gr[2];
    const float uv = (float)gl[3] + (float)gr[3];
    const float cnew = sig_mul_tanh(iv, uv) + fl*cl + fr*cr;
    const float hnew = sig_mul_tanh(ov, cnew);
    hUpHigh[((size_t)jn*256 + rr)*256 + k] = (h16)hnew;
    cPar[(size_t)m*256 + k] = (h16)cnew;
    s += (float)hT[vl*256 + k] + (float)hT[vr*256 + k];
  }
  atomicAdd(&rep[rr*HS + k], s);
}

// ------------- level kernel (lvl7/lvl6 only, proven R18 schedule) -----------
__global__ __launch_bounds__(256,3) void level_mfma(
    const h16* __restrict__ hChild, const h16* __restrict__ cChild,
    const h16* __restrict__ Wfrag,   // [cb=4][kc=8][f=16][lane=64][8]
    const float* __restrict__ biou, const float* __restrict__ Ufb,
    h16* __restrict__ hUpW, h16* __restrict__ cPar,
    int log2n, int cbN, int cOff, int ndOff){
  const int n = 1 << log2n;
  const int mask2 = 2*n - 1;
  __shared__ h16 ldsA[4*8*64*8];   // 32 KB
  __shared__ h16 ldsB[16*64*8];    // 16 KB
  const int t = threadIdx.x, w = t >> 6, l = t & 63;
  const int q = l >> 4, li = l & 15;
  const int waveR = w & 1, waveC = w >> 1;
  const int bx = blockIdx.x;

  {
    const int grow = bx*64 + w*16 + li;
    const int cidx = grow & mask2;
    const int rr   = grow >> (log2n + 1);
    const size_t abase = ((size_t)(cOff + cidx)*256 + rr)*256;
    #pragma unroll
    for (int kc=0; kc<8; ++kc)
      DMA16(hChild + abase + kc*32 + q*8, &ldsA[(w*8 + kc)*512]);
  }

  for (int cb=0; cb<cbN; ++cb){
    const int cbi = blockIdx.y*cbN + cb;            // 64-col group 0..3
    const int colBase = cbi*64;
    const h16* wfBase = Wfrag + (size_t)cbi*8*16*512 + (size_t)l*8;

    #pragma unroll
    for (int i=0; i<4; ++i)
      DMA16(wfBase + ((size_t)(w*4 + i))*512, &ldsB[(w*4 + i)*512]);
    __syncthreads();   // drains A-DMA (cb==0) + B(0) + prior epilogue reads

    f32x4 acc[4][2][2] = {};   // [gate f,i,o,u][rt][ct]
    #pragma unroll
    for (int kc=0; kc<8; ++kc){
      f16x8 aF[2], bF[4][2];
      #pragma unroll
      for (int rt=0; rt<2; ++rt)
        aF[rt] = *(const f16x8*)&ldsA[(((waveR*2 + rt)*8 + kc)*64 + l)*8];
      #pragma unroll
      for (int g=0; g<4; ++g)
        #pragma unroll
        for (int ct=0; ct<2; ++ct)
          bF[g][ct] = *(const f16x8*)&ldsB[((g*4 + waveC*2 + ct)*64 + l)*8];
      __syncthreads();   // all reads done
      if (kc < 7){
        #pragma unroll
        for (int i=0; i<4; ++i)
          DMA16(wfBase + ((size_t)(kc+1)*16 + w*4 + i)*512,
                &ldsB[(w*4 + i)*512]);
      }
      #pragma unroll
      for (int g=0; g<4; ++g)
        #pragma unroll
        for (int rt=0; rt<2; ++rt)
          #pragma unroll
          for (int ct=0; ct<2; ++ct)
            acc[g][rt][ct] = __builtin_amdgcn_mfma_f32_16x16x32_f16(
                aF[rt], bF[g][ct], acc[g][rt][ct], 0,0,0);
      __syncthreads();   // drains B(kc+1)
    }

    #pragma unroll
    for (int ct=0; ct<2; ++ct){
      const int c = colBase + waveC*32 + ct*16 + li;
      const float fb  = Ufb[c];
      const float bi_ = biou[c], bo_ = biou[256+c], bu_ = biou[512+c];
      #pragma unroll
      for (int rt=0; rt<2; ++rt){
        #pragma unroll
        for (int pp=0; pp<2; ++pp){
          const int crel = waveR*32 + rt*16 + q*4 + 2*pp;  // even child row (rel)
          const int m = bx*32 + (crel >> 1);               // global parent index
          const int rr2 = m >> log2n;
          const int jn = m & (n - 1);
          const float cl = (float)cChild[(size_t)(bx*64 + crel)*256 + c];
          const float cr = (float)cChild[(size_t)(bx*64 + crel + 1)*256 + c];
          const float fl = sigf(acc[0][rt][ct][2*pp]   + fb);
          const float fr = sigf(acc[0][rt][ct][2*pp+1] + fb);
          const float iv = acc[1][rt][ct][2*pp] + acc[1][rt][ct][2*pp+1] + bi_;
          const float ov = acc[2][rt][ct][2*pp] + acc[2][rt][ct][2*pp+1] + bo_;
          const float uv = acc[3][rt][ct][2*pp] + acc[3][rt][ct][2*pp+1] + bu_;
          const float cnew = sig_mul_tanh(iv, uv) + fl*cl + fr*cr;
          const float hnew = sig_mul_tanh(ov, cnew);
          hUpW[(((size_t)(ndOff + jn))*256 + rr2)*256 + c] = (h16)hnew;
          cPar[((size_t)m)*256 + c] = (h16)cnew;
        }
      }
    }
  }
}

// ------------- tree_tail: lvl5..0 fused, one block per tree -----------------
// h children in LDS A-frag layout (ping-pong A0/A1), c in plain [row][col]
// (C0/C1). B streamed per level from L2-resident Wfrag (proven schedule).
// rep for nodes 0..62 accumulated in ldsRep, flushed once per (tree,col).
template<int RT, int N>
__device__ __forceinline__ void tail_level(const h16* Ain, h16* Aout,
    const h16* Cin, h16* Cout, const h16* __restrict__ Wfrag,
    const float* __restrict__ biou, const float* __restrict__ Ufb,
    float* ldsRep, h16* Bs,
    int t, int w, int l, int q, int li, int waveR, int waveC){
  constexpr int rtCnt = (RT == 4) ? 2 : 1;
  for (int cb=0; cb<4; ++cb){
    const h16* wfBase = Wfrag + (size_t)cb*65536 + (size_t)l*8;
    #pragma unroll
    for (int i=0; i<4; ++i)
      DMA16(wfBase + ((size_t)(w*4 + i))*512, &Bs[(w*4 + i)*512]);
    __syncthreads();   // drains B(0) (+ initial A/C staging on first call)

    f32x4 acc[4][2][2] = {};
    for (int kc=0; kc<8; ++kc){
      f16x8 aF[2], bF[4][2];
      #pragma unroll
      for (int rt=0; rt<rtCnt; ++rt){
        const int rti = (RT == 4) ? (waveR*2 + rt) : ((RT == 2) ? waveR : 0);
        aF[rt] = *(const f16x8*)&Ain[((rti*8 + kc)*64 + l)*8];
      }
      #pragma unroll
      for (int g=0; g<4; ++g)
        #pragma unroll
        for (int ct=0; ct<2; ++ct)
          bF[g][ct] = *(const f16x8*)&Bs[((g*4 + waveC*2 + ct)*64 + l)*8];
      __syncthreads();   // reads done
      if (kc < 7){
        #pragma unroll
        for (int i=0; i<4; ++i)
          DMA16(wfBase + ((size_t)(kc+1)*16 + w*4 + i)*512,
                &Bs[(w*4 + i)*512]);
      }
      #pragma unroll
      for (int g=0; g<4; ++g)
        #pragma unroll
        for (int rt=0; rt<rtCnt; ++rt)
          #pragma unroll
          for (int ct=0; ct<2; ++ct)
            acc[g][rt][ct] = __builtin_amdgcn_mfma_f32_16x16x32_f16(
                aF[rt], bF[g][ct], acc[g][rt][ct], 0,0,0);
      __syncthreads();   // drains B(kc+1)
    }

    // epilogue: cell math; parent h -> Aout (frag layout), c -> Cout
    #pragma unroll
    for (int ct=0; ct<2; ++ct){
      const int c = cb*64 + waveC*32 + ct*16 + li;
      const float fb  = Ufb[c];
      const float bi_ = biou[c], bo_ = biou[256+c], bu_ = biou[512+c];
      float repPart = 0.f;
      #pragma unroll
      for (int rt=0; rt<rtCnt; ++rt){
        #pragma unroll
        for (int pp=0; pp<2; ++pp){
          const int crel = ((RT == 4) ? (waveR*32 + rt*16)
                           : (RT == 2) ? (waveR*16) : 0) + q*4 + 2*pp;
          const int pr = crel >> 1;
          const bool valid = (pr < N) && !(RT == 1 && waveR == 1);
          const float cl = (float)Cin[crel*256 + c];
          const float cr = (float)Cin[(crel+1)*256 + c];
          const float fl = sigf(acc[0][rt][ct][2*pp]   + fb);
          const float fr = sigf(acc[0][rt][ct][2*pp+1] + fb);
          const float iv = acc[1][rt][ct][2*pp] + acc[1][rt][ct][2*pp+1] + bi_;
          const float ov = acc[2][rt][ct][2*pp] + acc[2][rt][ct][2*pp+1] + bo_;
          const float uv = acc[3][rt][ct][2*pp] + acc[3][rt][ct][2*pp+1] + bu_;
          const float cnew = sig_mul_tanh(iv, uv) + fl*cl + fr*cr;
          const float hnew = sig_mul_tanh(ov, cnew);
          if (valid){
            const int kc2 = c >> 5, qq = (c >> 3) & 3, j = c & 7;
            const int tile = pr >> 4, li2 = pr & 15;
            Aout[((tile*8 + kc2)*64 + qq*16 + li2)*8 + j] = (h16)hnew;
            Cout[pr*256 + c] = (h16)cnew;
            repPart += hnew;
          }
        }
      }
      atomicAdd(&ldsRep[c], repPart);
    }
  }
  // zero-pad Aout rows [N,16) so next level's MFMA reads finite values
  if (N < 16){
    for (int pr=N; pr<16; ++pr){
      const int c2 = t;
      const int kc2 = c2 >> 5, qq = (c2 >> 3) & 3, j = c2 & 7;
      Aout[((0*8 + kc2)*64 + qq*16 + (pr & 15))*8 + j] = (h16)0.f;
    }
  }
}

__global__ __launch_bounds__(256,1) void tree_tail(
    const h16* __restrict__ hUpLow, const h16* __restrict__ cIn,
    const h16* __restrict__ Wfrag, const float* __restrict__ biou,
    const float* __restrict__ Ufb, float* __restrict__ rep){
  __shared__ h16 A0[4*8*64*8];   // 32 KB (64 child rows, frag layout)
  __shared__ h16 A1[2*8*64*8];   // 16 KB (<=32 rows)
  __shared__ h16 Bs[16*64*8];    // 16 KB
  __shared__ h16 C0[64*256];     // 32 KB
  __shared__ h16 C1[32*256];     // 16 KB
  __shared__ float ldsRep[256];  //  1 KB
  const int t = threadIdx.x, w = t >> 6, l = t & 63;
  const int q = l >> 4, li = l & 15;
  const int waveR = w & 1, waveC = w >> 1;
  const int rr = blockIdx.x;     // tree 0..255

  ldsRep[t] = 0.f;

  // stage A0: 64 child rows = lvl6 outputs, nodes 63..126 (node-major hUpLow)
  {
    const int jj = w*16 + li;
    const size_t abase = ((size_t)(63 + jj)*256 + rr)*256;
    #pragma unroll
    for (int kc=0; kc<8; ++kc)
      DMA16(hUpLow + abase + kc*32 + q*8, &A0[(w*8 + kc)*512]);
  }
  // stage C0: lvl6 c (cA), contiguous 32 KB per tree
  {
    const h16* src = cIn + (size_t)rr*16384 + (size_t)l*8;
    #pragma unroll
    for (int r2=0; r2<8; ++r2)
      DMA16(src + ((size_t)(r2*4 + w))*512, &C0[(r2*4 + w)*512]);
  }
  // first tail_level's B(0)+__syncthreads drains A0/C0 staging too.

  tail_level<4,32>(A0, A1, C0, C1, Wfrag, biou, Ufb, ldsRep, Bs, t,w,l,q,li,waveR,waveC);
  tail_level<2,16>(A1, A0, C1, C0, Wfrag, biou, Ufb, ldsRep, Bs, t,w,l,q,li,waveR,waveC);
  tail_level<1,8> (A0, A1, C0, C1, Wfrag, biou, Ufb, ldsRep, Bs, t,w,l,q,li,waveR,waveC);
  tail_level<1,4> (A1, A0, C1, C0, Wfrag, biou, Ufb, ldsRep, Bs, t,w,l,q,li,waveR,waveC);
  tail_level<1,2> (A0, A1, C0, C1, Wfrag, biou, Ufb, ldsRep, Bs, t,w,l,q,li,waveR,waveC);
  tail_level<1,1> (A1, A0, C1, C0, Wfrag, biou, Ufb, ldsRep, Bs, t,w,l,q,li,waveR,waveC);

  __syncthreads();
  atomicAdd(&rep[rr*HS + t], ldsRep[t]);
}

// ------------- rep accumulation (node-major hUp region) -------------
__global__ __launch_bounds__(256) void rep_accum(const h16* __restrict__ H,
    float* __restrict__ rep, int nrows, int chunk){
  const int r = blockIdx.y, k = threadIdx.x;
  const int n0 = blockIdx.x * chunk;
  int n1 = n0 + chunk; if (n1 > nrows) n1 = nrows;
  float s = 0.f;
  for (int nd = n0; nd < n1; ++nd)
    s += (float)H[((size_t)nd*256 + r)*HS + k];
  atomicAdd(&rep[r*HS + k], s);
}

// ------------- classifier -------------
__global__ __launch_bounds__(256) void cls_kernel(const float* __restrict__ rep,
    const float* __restrict__ clsw, const float* __restrict__ clsb,
    float* __restrict__ out){
  const int b = blockIdx.x, k = threadIdx.x;
  const float d = fabsf(rep[b*HS + k] - rep[(128+b)*HS + k]) * (1.0f/1023.0f);
  __shared__ float r0[256], r1[256];
  r0[k] = d * clsw[k];
  r1[k] = d * clsw[HS + k];
  __syncthreads();
  for (int off = 128; off > 0; off >>= 1){
    if (k < off){ r0[k] += r0[k+off]; r1[k] += r1[k+off]; }
    __syncthreads();
  }
  if (k == 0){
    out[b*2 + 0] = r0[0] + clsb[0];
    out[b*2 + 1] = r1[0] + clsb[1];
  }
}

extern "C" void kernel_launch(void* const* d_in, const int* in_sizes, int n_in,
                              void* d_out, int out_size, void* d_ws, size_t ws_size,
                              hipStream_t stream){
  const int*   types1 = (const int*)d_in[0];
  const int*   types2 = (const int*)d_in[1];
  const float* emb    = (const float*)d_in[2];
  const float* Wiou   = (const float*)d_in[3];
  const float* Uiou   = (const float*)d_in[4];
  const float* biou   = (const float*)d_in[5];
  const float* Ufw    = (const float*)d_in[6];
  const float* Ufb    = (const float*)d_in[7];
  const float* clsw   = (const float*)d_in[8];
  const float* clsb   = (const float*)d_in[9];
  float* out = (float*)d_out;

  // ---- overlay layout (h16 units). Total 116,588,544 h16 = 233.18 MB ----
  h16* ws      = (h16*)d_ws;
  h16* GT16    = ws;                         // 32,768,000 h16 = 65.5 MB
  h16* emb16   = ws + 24576000UL;            //  8,192,000
  h16* Wx16    = ws + 32768000UL;            //    196,608 (dead after swizzle)
  h16* hUpLow  = ws;                         // 16,711,680 (nodes 0..254)
  h16* cB      = ws + 16711680UL;            //  8,388,608
  h16* hT      = ws + 65536000UL;            //  8,192,000
  h16* cT      = ws + 73728000UL;            //  8,192,000
  h16* hUpHigh = ws + 81920000UL;            // 16,777,216 (nodes 255..510 local)
  h16* cA      = ws + 98697216UL;            // 16,777,216
  h16* W16     = ws + 115474432UL;           //    262,144
  h16* Wfrag   = ws + 115736576UL;           //    524,288
  float* rep   = (float*)(ws + 116260864UL); //     65,536 f32
  h16* WxFrag  = ws + 116391936UL;           //    196,608

  convert_all<<<4224, 256, 0, stream>>>(emb, Ufw, Uiou, Wiou, emb16, W16, Wx16, rep);
  swizzle_all<<<352, 256, 0, stream>>>(W16, Wx16, Wfrag, WxFrag);
  ht_mfma<<<500, 256, 0, stream>>>(emb16, WxFrag, biou, hT, cT);
  gt16_mfma<<<500, 256, 0, stream>>>(hT, Wfrag, biou, Ufb, GT16); // overwrites emb16
  lvl8_cell<<<2048, 256, 0, stream>>>(types1, types2, GT16, cT, hT,
                                      hUpHigh, cA, rep);

  // lvl7: children 65536, proven cbN=4 config (R20: 70.6us)
  level_mfma<<<dim3(1024, 1), 256, 0, stream>>>(
      hUpHigh, cA, Wfrag, biou, Ufb, hUpLow, cB, 7, 4, 0, 127);
  // lvl6: children 32768
  level_mfma<<<dim3(512, 1), 256, 0, stream>>>(
      hUpLow, cB, Wfrag, biou, Ufb, hUpLow, cA, 6, 4, 127, 63);
  // lvl5..0 fused: one block per tree
  tree_tail<<<256, 256, 0, stream>>>(hUpLow, cA, Wfrag, biou, Ufb, rep);

  rep_accum<<<dim3(2, B2), 256, 0, stream>>>(hUpLow + 63UL*65536UL, rep, 192, 96);
  rep_accum<<<dim3(2, B2), 256, 0, stream>>>(hUpHigh, rep, 256, 128);
  cls_kernel<<<128, 256, 0, stream>>>(rep, clsw, clsb, out);
}

// Round 11
// 456.579 us; speedup vs baseline: 1.0687x; 1.0687x over previous
//
#include <hip/hip_runtime.h>
#include <math.h>

// TreeLSTM MI355X — R23: R21 composition with the lvl7 grid bug fixed.
// R22 post-mortem: tree_tail (lvl5..0 fused, 1 block/tree) = 115us vs 25-40
// predicted — occupancy 11%, 805K LDS bank conflicts (frag-scatter stores +
// stride-512B C reads), 3MB serial Wfrag stream per block with zero TLP.
// Fifth failure of the "restructure execution" family (R13/R14/R15/R17/R22);
// only "remove work" rounds (R18/R19/R20/R21) ever won. R23 = pure revert to
// the best proven composition: R21's pipeline (ht_mfma fusion, fp16
// gate-interleaved GT16, lvl8_cell+leaf_rep fold, level_mfma for lvl<=5 at
// grid (children/64, 4)) with lvl7 restored to cbN=4 (R20-measured 70.6us;
// R21's cbN=2 "tail fix" was 76.0us from doubled A staging).
// Layout unchanged (233.18 MB).

typedef _Float16 h16;
typedef h16 f16x8 __attribute__((ext_vector_type(8)));
typedef h16 h16x4 __attribute__((ext_vector_type(4)));
typedef float f32x4 __attribute__((ext_vector_type(4)));

#define HS 256
#define NTREE 1023
#define B2 256

#define DMA16(gp, lp) __builtin_amdgcn_global_load_lds( \
    (const __attribute__((address_space(1))) void*)(gp), \
    (__attribute__((address_space(3))) void*)(lp), 16, 0, 0)

__device__ __forceinline__ float sigf(float x){
  return __builtin_amdgcn_rcpf(1.0f + exp2f(x * -1.44269504f));
}
// sigmoid(a)*tanh(b) in 3 trans (exp2,exp2,rcp). Clamp avoids E2=inf -> NaN.
__device__ __forceinline__ float sig_mul_tanh(float a, float b){
  const float E1 = exp2f(a * -1.44269504f);
  const float E2 = exp2f(fminf(b * -2.88539008f, 126.0f));
  return (1.0f - E2) * __builtin_amdgcn_rcpf((1.0f + E1) * (1.0f + E2));
}

// ------------- convert fp32 -> fp16 (emb, Ufw, Uiou, Wiou) + zero rep -------
__global__ __launch_bounds__(256) void convert_all(const float* __restrict__ emb,
    const float* __restrict__ Ufw, const float* __restrict__ Uiou,
    const float* __restrict__ Wiou, h16* __restrict__ emb16,
    h16* __restrict__ W16, h16* __restrict__ Wx16, float* __restrict__ rep){
  if (blockIdx.x < 64)
    ((float4*)rep)[blockIdx.x*256 + threadIdx.x] = make_float4(0.f,0.f,0.f,0.f);
  const size_t i0 = ((size_t)blockIdx.x*256 + threadIdx.x)*8;
  const float* src; h16* dst; size_t off;
  if (i0 < 8192000UL){ src = emb;  dst = emb16;       off = i0; }
  else if (i0 < 8257536UL){ src = Ufw;  dst = W16;        off = i0 - 8192000UL; }
  else if (i0 < 8454144UL){ src = Uiou; dst = W16+65536;  off = i0 - 8257536UL; }
  else               { src = Wiou; dst = Wx16;       off = i0 - 8454144UL; }
  const float4 v0 = *(const float4*)&src[off];
  const float4 v1 = *(const float4*)&src[off+4];
  f16x8 o;
  o[0]=(h16)v0.x; o[1]=(h16)v0.y; o[2]=(h16)v0.z; o[3]=(h16)v0.w;
  o[4]=(h16)v1.x; o[5]=(h16)v1.y; o[6]=(h16)v1.z; o[7]=(h16)v1.w;
  *(f16x8*)&dst[off] = o;
}

// ------------- swizzle W16 -> Wfrag (4 gates) and Wx16 -> WxFrag (3 gates) --
__global__ __launch_bounds__(256) void swizzle_all(const h16* __restrict__ W16,
    const h16* __restrict__ Wx16, h16* __restrict__ Wfrag,
    h16* __restrict__ WxFrag){
  const int tid = blockIdx.x*256 + threadIdx.x;   // 0..90111
  if (tid < 65536){
    const int lane = tid & 63;
    const int f    = (tid >> 6) & 15;
    const int kc   = (tid >> 10) & 7;
    const int cb   = tid >> 13;
    const int g = f >> 2, cf = f & 3;
    const int row = g*256 + cb*64 + cf*16 + (lane & 15);
    const int col = kc*32 + (lane >> 4)*8;
    const f16x8 v = *(const f16x8*)&W16[(size_t)row*256 + col];
    *(f16x8*)&Wfrag[(size_t)tid*8] = v;
  } else {
    const int t2 = tid - 65536;          // 0..24575
    const int lane = t2 & 63;
    const int frag = t2 >> 6;            // 0..383 = cb*96 + kc*12 + f
    const int cb  = frag / 96;
    const int rem = frag % 96;
    const int kc  = rem / 12;
    const int f   = rem % 12;
    const int g = f >> 2, cf = f & 3;    // g in {0,1,2} = i,o,u
    const int row = g*256 + cb*64 + cf*16 + (lane & 15);
    const int col = kc*32 + (lane >> 4)*8;
    const f16x8 v = *(const f16x8*)&Wx16[(size_t)row*256 + col];
    *(f16x8*)&WxFrag[(size_t)frag*512 + lane*8] = v;
  }
}

// ------------- hT,cT = leaf cell(emb @ Wx^T + b) per TYPE (fused) -----------
__global__ __launch_bounds__(256,3) void ht_mfma(const h16* __restrict__ emb16,
    const h16* __restrict__ WxFrag, const float* __restrict__ biou,
    h16* __restrict__ hT, h16* __restrict__ cT){
  __shared__ h16 ldsA[4*8*64*8];   // 32 KB
  __shared__ h16 ldsB[12*64*8];    // 12 KB
  const int t = threadIdx.x, w = t >> 6, l = t & 63;
  const int q = l >> 4, li = l & 15;
  const int waveR = w & 1, waveC = w >> 1;
  const int bx = blockIdx.x;

  {
    const int grow = bx*64 + w*16 + li;
    const size_t abase = (size_t)grow * 256;
    #pragma unroll
    for (int kc=0; kc<8; ++kc)
      DMA16(emb16 + abase + kc*32 + q*8, &ldsA[(w*8 + kc)*512]);
  }

  for (int cb=0; cb<4; ++cb){
    const h16* wfBase = WxFrag + (size_t)cb*8*12*512 + (size_t)l*8;

    #pragma unroll
    for (int i=0; i<3; ++i)
      DMA16(wfBase + ((size_t)(w*3 + i))*512, &ldsB[(w*3 + i)*512]);
    __syncthreads();   // drains A (cb0) + B(0)

    f32x4 acc[3][2][2] = {};   // [gate i,o,u][rt][ct]
    #pragma unroll
    for (int kc=0; kc<8; ++kc){
      f16x8 aF[2], bF[3][2];
      #pragma unroll
      for (int rt=0; rt<2; ++rt)
        aF[rt] = *(const f16x8*)&ldsA[(((waveR*2 + rt)*8 + kc)*64 + l)*8];
      #pragma unroll
      for (int g=0; g<3; ++g)
        #pragma unroll
        for (int ct=0; ct<2; ++ct)
          bF[g][ct] = *(const f16x8*)&ldsB[((g*4 + waveC*2 + ct)*64 + l)*8];
      __syncthreads();   // reads done
      if (kc < 7){
        #pragma unroll
        for (int i=0; i<3; ++i)
          DMA16(wfBase + ((size_t)(kc+1)*12 + w*3 + i)*512,
                &ldsB[(w*3 + i)*512]);
      }
      #pragma unroll
      for (int g=0; g<3; ++g)
        #pragma unroll
        for (int rt=0; rt<2; ++rt)
          #pragma unroll
          for (int ct=0; ct<2; ++ct)
            acc[g][rt][ct] = __builtin_amdgcn_mfma_f32_16x16x32_f16(
                aF[rt], bF[g][ct], acc[g][rt][ct], 0,0,0);
      __syncthreads();   // drains B(kc+1)
    }

    // epilogue: leaf cell from f32 pre-acts, write hT/cT
    #pragma unroll
    for (int ct=0; ct<2; ++ct){
      const int c = cb*64 + waveC*32 + ct*16 + li;
      const float bi = biou[c], bo = biou[256+c], bu = biou[512+c];
      #pragma unroll
      for (int rt=0; rt<2; ++rt){
        #pragma unroll
        for (int reg=0; reg<4; ++reg){
          const int row = bx*64 + waveR*32 + rt*16 + q*4 + reg;
          const float iv = acc[0][rt][ct][reg] + bi;
          const float ov = acc[1][rt][ct][reg] + bo;
          const float uv = acc[2][rt][ct][reg] + bu;
          const float cc = sig_mul_tanh(iv, uv);
          const float hh = sig_mul_tanh(ov, cc);
          hT[(size_t)row*256 + c] = (h16)hh;
          cT[(size_t)row*256 + c] = (h16)cc;
        }
      }
    }
  }
}

// ------------- GT16 = [Ufw;Uiou] @ hT^T per type, h16x4 interleaved ---------
__global__ __launch_bounds__(256,3) void gt16_mfma(const h16* __restrict__ hT,
    const h16* __restrict__ Wfrag, const float* __restrict__ biou,
    const float* __restrict__ Ufb, h16* __restrict__ GT16){
  __shared__ h16 ldsA[4*8*64*8];   // 32 KB
  __shared__ h16 ldsB[16*64*8];    // 16 KB
  const int t = threadIdx.x, w = t >> 6, l = t & 63;
  const int q = l >> 4, li = l & 15;
  const int waveR = w & 1, waveC = w >> 1;
  const int bx = blockIdx.x;

  {
    const int grow = bx*64 + w*16 + li;
    const size_t abase = (size_t)grow * 256;
    #pragma unroll
    for (int kc=0; kc<8; ++kc)
      DMA16(hT + abase + kc*32 + q*8, &ldsA[(w*8 + kc)*512]);
  }

  for (int cb=0; cb<4; ++cb){
    const h16* wfBase = Wfrag + (size_t)cb*8*16*512 + (size_t)l*8;

    #pragma unroll
    for (int i=0; i<4; ++i)
      DMA16(wfBase + ((size_t)(w*4 + i))*512, &ldsB[(w*4 + i)*512]);
    __syncthreads();

    f32x4 acc[4][2][2] = {};
    #pragma unroll
    for (int kc=0; kc<8; ++kc){
      f16x8 aF[2], bF[4][2];
      #pragma unroll
      for (int rt=0; rt<2; ++rt)
        aF[rt] = *(const f16x8*)&ldsA[(((waveR*2 + rt)*8 + kc)*64 + l)*8];
      #pragma unroll
      for (int g=0; g<4; ++g)
        #pragma unroll
        for (int ct=0; ct<2; ++ct)
          bF[g][ct] = *(const f16x8*)&ldsB[((g*4 + waveC*2 + ct)*64 + l)*8];
      __syncthreads();
      if (kc < 7){
        #pragma unroll
        for (int i=0; i<4; ++i)
          DMA16(wfBase + ((size_t)(kc+1)*16 + w*4 + i)*512,
                &ldsB[(w*4 + i)*512]);
      }
      #pragma unroll
      for (int g=0; g<4; ++g)
        #pragma unroll
        for (int rt=0; rt<2; ++rt)
          #pragma unroll
          for (int ct=0; ct<2; ++ct)
            acc[g][rt][ct] = __builtin_amdgcn_mfma_f32_16x16x32_f16(
                aF[rt], bF[g][ct], acc[g][rt][ct], 0,0,0);
      __syncthreads();
    }

    #pragma unroll
    for (int ct=0; ct<2; ++ct){
      const int c = cb*64 + waveC*32 + ct*16 + li;
      const float fb  = Ufb[c];
      const float bi2 = 0.5f*biou[c], bo2 = 0.5f*biou[256+c], bu2 = 0.5f*biou[512+c];
      #pragma unroll
      for (int rt=0; rt<2; ++rt){
        #pragma unroll
        for (int reg=0; reg<4; ++reg){
          const int row = bx*64 + waveR*32 + rt*16 + q*4 + reg;
          h16x4 o;
          o[0] = (h16)(acc[0][rt][ct][reg] + fb);
          o[1] = (h16)(acc[1][rt][ct][reg] + bi2);
          o[2] = (h16)(acc[2][rt][ct][reg] + bo2);
          o[3] = (h16)(acc[3][rt][ct][reg] + bu2);
          *(h16x4*)&GT16[(size_t)row*1024 + c*4] = o;
        }
      }
    }
  }
}

// ------------- lvl8: gather+cell + leaf-rep fold (no MFMA/LDS/barriers) -----
__global__ __launch_bounds__(256) void lvl8_cell(const int* __restrict__ t1,
    const int* __restrict__ t2, const h16* __restrict__ GT16,
    const h16* __restrict__ cT, const h16* __restrict__ hT,
    h16* __restrict__ hUpHigh, h16* __restrict__ cPar,
    float* __restrict__ rep){
  const int k = threadIdx.x;
  const int m0 = blockIdx.x*32;
  const int rr = m0 >> 8;
  const int* tp = (rr < 128) ? t1 : t2;
  const int b = rr & 127;
  float s = 0.f;
  #pragma unroll 4
  for (int p=0; p<32; ++p){
    const int m = m0 + p, jn = m & 255;
    const size_t vl = (size_t)tp[b*NTREE + 511 + 2*jn];
    const size_t vr = (size_t)tp[b*NTREE + 512 + 2*jn];
    const h16x4 gl = *(const h16x4*)&GT16[vl*1024 + k*4];
    const h16x4 gr = *(const h16x4*)&GT16[vr*1024 + k*4];
    const float cl = (float)cT[vl*256 + k];
    const float cr = (float)cT[vr*256 + k];
    const float fl = sigf((float)gl[0]);
    const float fr = sigf((float)gr[0]);
    const float iv = (float)gl[1] + (float)gr[1];
    const float ov = (float)gl[2] + (float)gr[2];
    const float uv = (float)gl[3] + (float)gr[3];
    const float cnew = sig_mul_tanh(iv, uv) + fl*cl + fr*cr;
    const float hnew = sig_mul_tanh(ov, cnew);
    hUpHigh[((size_t)jn*256 + rr)*256 + k] = (h16)hnew;
    cPar[(size_t)m*256 + k] = (h16)cnew;
    s += (float)hT[vl*256 + k] + (float)hT[vr*256 + k];
  }
  atomicAdd(&rep[rr*HS + k], s);
}

// ------------- level kernel (non-leaf levels, proven R18 schedule) ----------
__global__ __launch_bounds__(256,3) void level_mfma(
    const h16* __restrict__ hChild, const h16* __restrict__ cChild,
    const h16* __restrict__ Wfrag,   // [cb=4][kc=8][f=16][lane=64][8]
    const float* __restrict__ biou, const float* __restrict__ Ufb,
    h16* __restrict__ hUpW, h16* __restrict__ cPar,
    int log2n, int cbN, int cOff, int ndOff){
  const int n = 1 << log2n;
  const int mask2 = 2*n - 1;
  __shared__ h16 ldsA[4*8*64*8];   // 32 KB
  __shared__ h16 ldsB[16*64*8];    // 16 KB
  const int t = threadIdx.x, w = t >> 6, l = t & 63;
  const int q = l >> 4, li = l & 15;
  const int waveR = w & 1, waveC = w >> 1;
  const int bx = blockIdx.x;

  // ---- stage A once: wave w stages rowFrag R=w, kc=0..7 (frag-order) ----
  {
    const int grow = bx*64 + w*16 + li;
    const int cidx = grow & mask2;
    const int rr   = grow >> (log2n + 1);
    const size_t abase = ((size_t)(cOff + cidx)*256 + rr)*256;
    #pragma unroll
    for (int kc=0; kc<8; ++kc)
      DMA16(hChild + abase + kc*32 + q*8, &ldsA[(w*8 + kc)*512]);
  }

  for (int cb=0; cb<cbN; ++cb){
    const int cbi = blockIdx.y*cbN + cb;            // 64-col group 0..3
    const int colBase = cbi*64;
    const h16* wfBase = Wfrag + (size_t)cbi*8*16*512 + (size_t)l*8;

    // prologue: DMA B(kc=0)
    #pragma unroll
    for (int i=0; i<4; ++i)
      DMA16(wfBase + ((size_t)(w*4 + i))*512, &ldsB[(w*4 + i)*512]);
    __syncthreads();   // drains A-DMA (cb==0) + B(0) + prior epilogue reads

    f32x4 acc[4][2][2] = {};   // [gate f,i,o,u][rt][ct]
    #pragma unroll
    for (int kc=0; kc<8; ++kc){
      f16x8 aF[2], bF[4][2];
      #pragma unroll
      for (int rt=0; rt<2; ++rt)
        aF[rt] = *(const f16x8*)&ldsA[(((waveR*2 + rt)*8 + kc)*64 + l)*8];
      #pragma unroll
      for (int g=0; g<4; ++g)
        #pragma unroll
        for (int ct=0; ct<2; ++ct)
          bF[g][ct] = *(const f16x8*)&ldsB[((g*4 + waveC*2 + ct)*64 + l)*8];
      __syncthreads();   // all reads done
      if (kc < 7){
        #pragma unroll
        for (int i=0; i<4; ++i)
          DMA16(wfBase + ((size_t)(kc+1)*16 + w*4 + i)*512,
                &ldsB[(w*4 + i)*512]);
      }
      #pragma unroll
      for (int g=0; g<4; ++g)
        #pragma unroll
        for (int rt=0; rt<2; ++rt)
          #pragma unroll
          for (int ct=0; ct<2; ++ct)
            acc[g][rt][ct] = __builtin_amdgcn_mfma_f32_16x16x32_f16(
                aF[rt], bF[g][ct], acc[g][rt][ct], 0,0,0);
      __syncthreads();   // drains B(kc+1)
    }

    // ---- epilogue (all lane-local; sibling pairs = adjacent C regs) ----
    #pragma unroll
    for (int ct=0; ct<2; ++ct){
      const int c = colBase + waveC*32 + ct*16 + li;
      const float fb  = Ufb[c];
      const float bi_ = biou[c], bo_ = biou[256+c], bu_ = biou[512+c];
      #pragma unroll
      for (int rt=0; rt<2; ++rt){
        #pragma unroll
        for (int pp=0; pp<2; ++pp){
          const int crel = waveR*32 + rt*16 + q*4 + 2*pp;  // even child row (rel)
          const int m = bx*32 + (crel >> 1);               // global parent index
          const int rr2 = m >> log2n;
          const int jn = m & (n - 1);
          const float cl = (float)cChild[(size_t)(bx*64 + crel)*256 + c];
          const float cr = (float)cChild[(size_t)(bx*64 + crel + 1)*256 + c];
          const float fl = sigf(acc[0][rt][ct][2*pp]   + fb);
          const float fr = sigf(acc[0][rt][ct][2*pp+1] + fb);
          const float iv = acc[1][rt][ct][2*pp] + acc[1][rt][ct][2*pp+1] + bi_;
          const float ov = acc[2][rt][ct][2*pp] + acc[2][rt][ct][2*pp+1] + bo_;
          const float uv = acc[3][rt][ct][2*pp] + acc[3][rt][ct][2*pp+1] + bu_;
          const float cnew = sig_mul_tanh(iv, uv) + fl*cl + fr*cr;
          const float hnew = sig_mul_tanh(ov, cnew);
          hUpW[(((size_t)(ndOff + jn))*256 + rr2)*256 + c] = (h16)hnew;
          cPar[((size_t)m)*256 + c] = (h16)cnew;
        }
      }
    }
  }
}

// ------------- rep accumulation (internal nodes, node-major hUp region) -----
__global__ __launch_bounds__(256) void rep_accum(const h16* __restrict__ H,
    float* __restrict__ rep, int nrows, int chunk){
  const int r = blockIdx.y, k = threadIdx.x;
  const int n0 = blockIdx.x * chunk;
  int n1 = n0 + chunk; if (n1 > nrows) n1 = nrows;
  float s = 0.f;
  for (int nd = n0; nd < n1; ++nd)
    s += (float)H[((size_t)nd*256 + r)*HS + k];
  atomicAdd(&rep[r*HS + k], s);
}

// ------------- classifier -------------
__global__ __launch_bounds__(256) void cls_kernel(const float* __restrict__ rep,
    const float* __restrict__ clsw, const float* __restrict__ clsb,
    float* __restrict__ out){
  const int b = blockIdx.x, k = threadIdx.x;
  const float d = fabsf(rep[b*HS + k] - rep[(128+b)*HS + k]) * (1.0f/1023.0f);
  __shared__ float r0[256], r1[256];
  r0[k] = d * clsw[k];
  r1[k] = d * clsw[HS + k];
  __syncthreads();
  for (int off = 128; off > 0; off >>= 1){
    if (k < off){ r0[k] += r0[k+off]; r1[k] += r1[k+off]; }
    __syncthreads();
  }
  if (k == 0){
    out[b*2 + 0] = r0[0] + clsb[0];
    out[b*2 + 1] = r1[0] + clsb[1];
  }
}

extern "C" void kernel_launch(void* const* d_in, const int* in_sizes, int n_in,
                              void* d_out, int out_size, void* d_ws, size_t ws_size,
                              hipStream_t stream){
  const int*   types1 = (const int*)d_in[0];
  const int*   types2 = (const int*)d_in[1];
  const float* emb    = (const float*)d_in[2];
  const float* Wiou   = (const float*)d_in[3];
  const float* Uiou   = (const float*)d_in[4];
  const float* biou   = (const float*)d_in[5];
  const float* Ufw    = (const float*)d_in[6];
  const float* Ufb    = (const float*)d_in[7];
  const float* clsw   = (const float*)d_in[8];
  const float* clsb   = (const float*)d_in[9];
  float* out = (float*)d_out;

  // ---- overlay layout (h16 units). Total 116,588,544 h16 = 233.18 MB ----
  h16* ws      = (h16*)d_ws;
  // GT16 [0, 32,768,000) overlays emb16 (dead after ht_mfma);
  // hUpLow+cB overlay GT16 (dead after lvl8_cell).
  h16* GT16    = ws;                         // 32,768,000 h16 = 65.5 MB
  h16* emb16   = ws + 24576000UL;            //  8,192,000
  h16* Wx16    = ws + 32768000UL;            //    196,608 (dead after swizzle)
  h16* hUpLow  = ws;                         // 16,711,680 (nodes 0..254)
  h16* cB      = ws + 16711680UL;            //  8,388,608
  h16* hT      = ws + 65536000UL;            //  8,192,000
  h16* cT      = ws + 73728000UL;            //  8,192,000
  h16* hUpHigh = ws + 81920000UL;            // 16,777,216 (nodes 255..510 local)
  h16* cA      = ws + 98697216UL;            // 16,777,216
  h16* W16     = ws + 115474432UL;           //    262,144
  h16* Wfrag   = ws + 115736576UL;           //    524,288
  float* rep   = (float*)(ws + 116260864UL); //     65,536 f32
  h16* WxFrag  = ws + 116391936UL;           //    196,608

  convert_all<<<4224, 256, 0, stream>>>(emb, Ufw, Uiou, Wiou, emb16, W16, Wx16, rep);
  swizzle_all<<<352, 256, 0, stream>>>(W16, Wx16, Wfrag, WxFrag);
  ht_mfma<<<500, 256, 0, stream>>>(emb16, WxFrag, biou, hT, cT);
  gt16_mfma<<<500, 256, 0, stream>>>(hT, Wfrag, biou, Ufb, GT16); // overwrites emb16
  lvl8_cell<<<2048, 256, 0, stream>>>(types1, types2, GT16, cT, hT,
                                      hUpHigh, cA, rep);

  const h16* cprev = cA;
  for (int lvl = 7; lvl >= 0; --lvl){
    const int children = 512 << lvl;        // B2 * 2n
    const int cbN = (lvl >= 6) ? 4 : 1;     // big levels: y=1, col loop in-block
    h16* cout = ((8 - lvl) & 1) ? cB : cA;
    const h16* hin = (lvl == 7) ? hUpHigh : hUpLow;
    const int cOff  = (lvl == 7) ? 0 : ((1 << (lvl + 1)) - 1);
    const int ndOff = (1 << lvl) - 1;
    level_mfma<<<dim3(children/64, 4/cbN), 256, 0, stream>>>(
        hin, cprev, Wfrag, biou, Ufb, hUpLow, cout,
        lvl, cbN, cOff, ndOff);
    cprev = cout;
  }
  rep_accum<<<dim3(2, B2), 256, 0, stream>>>(hUpLow,  rep, 255, 128);
  rep_accum<<<dim3(2, B2), 256, 0, stream>>>(hUpHigh, rep, 256, 128);
  cls_kernel<<<128, 256, 0, stream>>>(rep, clsw, clsb, out);
}

// Round 12
// 416.214 us; speedup vs baseline: 1.1724x; 1.0970x over previous
//
#include <hip/hip_runtime.h>
#include <math.h>

// TreeLSTM MI355X — R24: fold rep accumulation into producers.
// R23 post-mortem: lvl7 restored to 70.9us/39.9MB (R20 profile ✓) but total
// 456.6 vs R21's 449.5 — ±7us codegen/noise band => plateau where only clean
// work-removal registers. R24 removes the last re-scan: rep_accum read 48MB
// of hUp (h we just computed in registers) purely to row-sum into rep.
//  1) lvl8_cell: s += hnew (rr block-constant) — hUpHigh scan (32MB) gone.
//  2) level_mfma lvl7/6/5 (log2n>=5 => rr2=(bx*32)>>log2n block-constant):
//     per-thread partials -> ldsRep[256] (f32 LDS atomics, 2/thread/cb),
//     one global atomicAdd per (block,col). LDS 48->49.2KB, still 3 blk/CU.
//  3) rep_accum: one launch, nodes 0..30 only (lvl<=4 outputs, 4MB).
// Expect -7..-12us net; if >=455 the fold is noise-negative and we've
// converged. Layout unchanged (233.18 MB).

typedef _Float16 h16;
typedef h16 f16x8 __attribute__((ext_vector_type(8)));
typedef h16 h16x4 __attribute__((ext_vector_type(4)));
typedef float f32x4 __attribute__((ext_vector_type(4)));

#define HS 256
#define NTREE 1023
#define B2 256

#define DMA16(gp, lp) __builtin_amdgcn_global_load_lds( \
    (const __attribute__((address_space(1))) void*)(gp), \
    (__attribute__((address_space(3))) void*)(lp), 16, 0, 0)

__device__ __forceinline__ float sigf(float x){
  return __builtin_amdgcn_rcpf(1.0f + exp2f(x * -1.44269504f));
}
// sigmoid(a)*tanh(b) in 3 trans (exp2,exp2,rcp). Clamp avoids E2=inf -> NaN.
__device__ __forceinline__ float sig_mul_tanh(float a, float b){
  const float E1 = exp2f(a * -1.44269504f);
  const float E2 = exp2f(fminf(b * -2.88539008f, 126.0f));
  return (1.0f - E2) * __builtin_amdgcn_rcpf((1.0f + E1) * (1.0f + E2));
}

// ------------- convert fp32 -> fp16 (emb, Ufw, Uiou, Wiou) + zero rep -------
__global__ __launch_bounds__(256) void convert_all(const float* __restrict__ emb,
    const float* __restrict__ Ufw, const float* __restrict__ Uiou,
    const float* __restrict__ Wiou, h16* __restrict__ emb16,
    h16* __restrict__ W16, h16* __restrict__ Wx16, float* __restrict__ rep){
  if (blockIdx.x < 64)
    ((float4*)rep)[blockIdx.x*256 + threadIdx.x] = make_float4(0.f,0.f,0.f,0.f);
  const size_t i0 = ((size_t)blockIdx.x*256 + threadIdx.x)*8;
  const float* src; h16* dst; size_t off;
  if (i0 < 8192000UL){ src = emb;  dst = emb16;       off = i0; }
  else if (i0 < 8257536UL){ src = Ufw;  dst = W16;        off = i0 - 8192000UL; }
  else if (i0 < 8454144UL){ src = Uiou; dst = W16+65536;  off = i0 - 8257536UL; }
  else               { src = Wiou; dst = Wx16;       off = i0 - 8454144UL; }
  const float4 v0 = *(const float4*)&src[off];
  const float4 v1 = *(const float4*)&src[off+4];
  f16x8 o;
  o[0]=(h16)v0.x; o[1]=(h16)v0.y; o[2]=(h16)v0.z; o[3]=(h16)v0.w;
  o[4]=(h16)v1.x; o[5]=(h16)v1.y; o[6]=(h16)v1.z; o[7]=(h16)v1.w;
  *(f16x8*)&dst[off] = o;
}

// ------------- swizzle W16 -> Wfrag (4 gates) and Wx16 -> WxFrag (3 gates) --
__global__ __launch_bounds__(256) void swizzle_all(const h16* __restrict__ W16,
    const h16* __restrict__ Wx16, h16* __restrict__ Wfrag,
    h16* __restrict__ WxFrag){
  const int tid = blockIdx.x*256 + threadIdx.x;   // 0..90111
  if (tid < 65536){
    const int lane = tid & 63;
    const int f    = (tid >> 6) & 15;
    const int kc   = (tid >> 10) & 7;
    const int cb   = tid >> 13;
    const int g = f >> 2, cf = f & 3;
    const int row = g*256 + cb*64 + cf*16 + (lane & 15);
    const int col = kc*32 + (lane >> 4)*8;
    const f16x8 v = *(const f16x8*)&W16[(size_t)row*256 + col];
    *(f16x8*)&Wfrag[(size_t)tid*8] = v;
  } else {
    const int t2 = tid - 65536;          // 0..24575
    const int lane = t2 & 63;
    const int frag = t2 >> 6;            // 0..383 = cb*96 + kc*12 + f
    const int cb  = frag / 96;
    const int rem = frag % 96;
    const int kc  = rem / 12;
    const int f   = rem % 12;
    const int g = f >> 2, cf = f & 3;    // g in {0,1,2} = i,o,u
    const int row = g*256 + cb*64 + cf*16 + (lane & 15);
    const int col = kc*32 + (lane >> 4)*8;
    const f16x8 v = *(const f16x8*)&Wx16[(size_t)row*256 + col];
    *(f16x8*)&WxFrag[(size_t)frag*512 + lane*8] = v;
  }
}

// ------------- hT,cT = leaf cell(emb @ Wx^T + b) per TYPE (fused) -----------
__global__ __launch_bounds__(256,3) void ht_mfma(const h16* __restrict__ emb16,
    const h16* __restrict__ WxFrag, const float* __restrict__ biou,
    h16* __restrict__ hT, h16* __restrict__ cT){
  __shared__ h16 ldsA[4*8*64*8];   // 32 KB
  __shared__ h16 ldsB[12*64*8];    // 12 KB
  const int t = threadIdx.x, w = t >> 6, l = t & 63;
  const int q = l >> 4, li = l & 15;
  const int waveR = w & 1, waveC = w >> 1;
  const int bx = blockIdx.x;

  {
    const int grow = bx*64 + w*16 + li;
    const size_t abase = (size_t)grow * 256;
    #pragma unroll
    for (int kc=0; kc<8; ++kc)
      DMA16(emb16 + abase + kc*32 + q*8, &ldsA[(w*8 + kc)*512]);
  }

  for (int cb=0; cb<4; ++cb){
    const h16* wfBase = WxFrag + (size_t)cb*8*12*512 + (size_t)l*8;

    #pragma unroll
    for (int i=0; i<3; ++i)
      DMA16(wfBase + ((size_t)(w*3 + i))*512, &ldsB[(w*3 + i)*512]);
    __syncthreads();   // drains A (cb0) + B(0)

    f32x4 acc[3][2][2] = {};   // [gate i,o,u][rt][ct]
    #pragma unroll
    for (int kc=0; kc<8; ++kc){
      f16x8 aF[2], bF[3][2];
      #pragma unroll
      for (int rt=0; rt<2; ++rt)
        aF[rt] = *(const f16x8*)&ldsA[(((waveR*2 + rt)*8 + kc)*64 + l)*8];
      #pragma unroll
      for (int g=0; g<3; ++g)
        #pragma unroll
        for (int ct=0; ct<2; ++ct)
          bF[g][ct] = *(const f16x8*)&ldsB[((g*4 + waveC*2 + ct)*64 + l)*8];
      __syncthreads();   // reads done
      if (kc < 7){
        #pragma unroll
        for (int i=0; i<3; ++i)
          DMA16(wfBase + ((size_t)(kc+1)*12 + w*3 + i)*512,
                &ldsB[(w*3 + i)*512]);
      }
      #pragma unroll
      for (int g=0; g<3; ++g)
        #pragma unroll
        for (int rt=0; rt<2; ++rt)
          #pragma unroll
          for (int ct=0; ct<2; ++ct)
            acc[g][rt][ct] = __builtin_amdgcn_mfma_f32_16x16x32_f16(
                aF[rt], bF[g][ct], acc[g][rt][ct], 0,0,0);
      __syncthreads();   // drains B(kc+1)
    }

    // epilogue: leaf cell from f32 pre-acts, write hT/cT
    #pragma unroll
    for (int ct=0; ct<2; ++ct){
      const int c = cb*64 + waveC*32 + ct*16 + li;
      const float bi = biou[c], bo = biou[256+c], bu = biou[512+c];
      #pragma unroll
      for (int rt=0; rt<2; ++rt){
        #pragma unroll
        for (int reg=0; reg<4; ++reg){
          const int row = bx*64 + waveR*32 + rt*16 + q*4 + reg;
          const float iv = acc[0][rt][ct][reg] + bi;
          const float ov = acc[1][rt][ct][reg] + bo;
          const float uv = acc[2][rt][ct][reg] + bu;
          const float cc = sig_mul_tanh(iv, uv);
          const float hh = sig_mul_tanh(ov, cc);
          hT[(size_t)row*256 + c] = (h16)hh;
          cT[(size_t)row*256 + c] = (h16)cc;
        }
      }
    }
  }
}

// ------------- GT16 = [Ufw;Uiou] @ hT^T per type, h16x4 interleaved ---------
__global__ __launch_bounds__(256,3) void gt16_mfma(const h16* __restrict__ hT,
    const h16* __restrict__ Wfrag, const float* __restrict__ biou,
    const float* __restrict__ Ufb, h16* __restrict__ GT16){
  __shared__ h16 ldsA[4*8*64*8];   // 32 KB
  __shared__ h16 ldsB[16*64*8];    // 16 KB
  const int t = threadIdx.x, w = t >> 6, l = t & 63;
  const int q = l >> 4, li = l & 15;
  const int waveR = w & 1, waveC = w >> 1;
  const int bx = blockIdx.x;

  {
    const int grow = bx*64 + w*16 + li;
    const size_t abase = (size_t)grow * 256;
    #pragma unroll
    for (int kc=0; kc<8; ++kc)
      DMA16(hT + abase + kc*32 + q*8, &ldsA[(w*8 + kc)*512]);
  }

  for (int cb=0; cb<4; ++cb){
    const h16* wfBase = Wfrag + (size_t)cb*8*16*512 + (size_t)l*8;

    #pragma unroll
    for (int i=0; i<4; ++i)
      DMA16(wfBase + ((size_t)(w*4 + i))*512, &ldsB[(w*4 + i)*512]);
    __syncthreads();

    f32x4 acc[4][2][2] = {};
    #pragma unroll
    for (int kc=0; kc<8; ++kc){
      f16x8 aF[2], bF[4][2];
      #pragma unroll
      for (int rt=0; rt<2; ++rt)
        aF[rt] = *(const f16x8*)&ldsA[(((waveR*2 + rt)*8 + kc)*64 + l)*8];
      #pragma unroll
      for (int g=0; g<4; ++g)
        #pragma unroll
        for (int ct=0; ct<2; ++ct)
          bF[g][ct] = *(const f16x8*)&ldsB[((g*4 + waveC*2 + ct)*64 + l)*8];
      __syncthreads();
      if (kc < 7){
        #pragma unroll
        for (int i=0; i<4; ++i)
          DMA16(wfBase + ((size_t)(kc+1)*16 + w*4 + i)*512,
                &ldsB[(w*4 + i)*512]);
      }
      #pragma unroll
      for (int g=0; g<4; ++g)
        #pragma unroll
        for (int rt=0; rt<2; ++rt)
          #pragma unroll
          for (int ct=0; ct<2; ++ct)
            acc[g][rt][ct] = __builtin_amdgcn_mfma_f32_16x16x32_f16(
                aF[rt], bF[g][ct], acc[g][rt][ct], 0,0,0);
      __syncthreads();
    }

    #pragma unroll
    for (int ct=0; ct<2; ++ct){
      const int c = cb*64 + waveC*32 + ct*16 + li;
      const float fb  = Ufb[c];
      const float bi2 = 0.5f*biou[c], bo2 = 0.5f*biou[256+c], bu2 = 0.5f*biou[512+c];
      #pragma unroll
      for (int rt=0; rt<2; ++rt){
        #pragma unroll
        for (int reg=0; reg<4; ++reg){
          const int row = bx*64 + waveR*32 + rt*16 + q*4 + reg;
          h16x4 o;
          o[0] = (h16)(acc[0][rt][ct][reg] + fb);
          o[1] = (h16)(acc[1][rt][ct][reg] + bi2);
          o[2] = (h16)(acc[2][rt][ct][reg] + bo2);
          o[3] = (h16)(acc[3][rt][ct][reg] + bu2);
          *(h16x4*)&GT16[(size_t)row*1024 + c*4] = o;
        }
      }
    }
  }
}

// ------------- lvl8: gather+cell + leaf-rep + parent-rep fold ---------------
__global__ __launch_bounds__(256) void lvl8_cell(const int* __restrict__ t1,
    const int* __restrict__ t2, const h16* __restrict__ GT16,
    const h16* __restrict__ cT, const h16* __restrict__ hT,
    h16* __restrict__ hUpHigh, h16* __restrict__ cPar,
    float* __restrict__ rep){
  const int k = threadIdx.x;
  const int m0 = blockIdx.x*32;
  const int rr = m0 >> 8;
  const int* tp = (rr < 128) ? t1 : t2;
  const int b = rr & 127;
  float s = 0.f;
  #pragma unroll 4
  for (int p=0; p<32; ++p){
    const int m = m0 + p, jn = m & 255;
    const size_t vl = (size_t)tp[b*NTREE + 511 + 2*jn];
    const size_t vr = (size_t)tp[b*NTREE + 512 + 2*jn];
    const h16x4 gl = *(const h16x4*)&GT16[vl*1024 + k*4];
    const h16x4 gr = *(const h16x4*)&GT16[vr*1024 + k*4];
    const float cl = (float)cT[vl*256 + k];
    const float cr = (float)cT[vr*256 + k];
    const float fl = sigf((float)gl[0]);
    const float fr = sigf((float)gr[0]);
    const float iv = (float)gl[1] + (float)gr[1];
    const float ov = (float)gl[2] + (float)gr[2];
    const float uv = (float)gl[3] + (float)gr[3];
    const float cnew = sig_mul_tanh(iv, uv) + fl*cl + fr*cr;
    const float hnew = sig_mul_tanh(ov, cnew);
    hUpHigh[((size_t)jn*256 + rr)*256 + k] = (h16)hnew;
    cPar[(size_t)m*256 + k] = (h16)cnew;
    s += (float)hT[vl*256 + k] + (float)hT[vr*256 + k] + hnew;  // leaves + parent
  }
  atomicAdd(&rep[rr*HS + k], s);
}

// ------------- level kernel (non-leaf levels, proven R18 schedule) ----------
// repFold (log2n>=5 only): rr2 = (bx*32)>>log2n is block-constant; fold
// per-thread h-sums into ldsRep[256] and atomicAdd once per (block,col).
__global__ __launch_bounds__(256,3) void level_mfma(
    const h16* __restrict__ hChild, const h16* __restrict__ cChild,
    const h16* __restrict__ Wfrag,   // [cb=4][kc=8][f=16][lane=64][8]
    const float* __restrict__ biou, const float* __restrict__ Ufb,
    h16* __restrict__ hUpW, h16* __restrict__ cPar, float* __restrict__ rep,
    int log2n, int cbN, int cOff, int ndOff, int repFold){
  const int n = 1 << log2n;
  const int mask2 = 2*n - 1;
  __shared__ h16 ldsA[4*8*64*8];   // 32 KB
  __shared__ h16 ldsB[16*64*8];    // 16 KB
  __shared__ float ldsRep[256];    //  1 KB
  const int t = threadIdx.x, w = t >> 6, l = t & 63;
  const int q = l >> 4, li = l & 15;
  const int waveR = w & 1, waveC = w >> 1;
  const int bx = blockIdx.x;

  if (repFold) ldsRep[t] = 0.f;    // first __syncthreads orders vs epilogue

  // ---- stage A once: wave w stages rowFrag R=w, kc=0..7 (frag-order) ----
  {
    const int grow = bx*64 + w*16 + li;
    const int cidx = grow & mask2;
    const int rr   = grow >> (log2n + 1);
    const size_t abase = ((size_t)(cOff + cidx)*256 + rr)*256;
    #pragma unroll
    for (int kc=0; kc<8; ++kc)
      DMA16(hChild + abase + kc*32 + q*8, &ldsA[(w*8 + kc)*512]);
  }

  for (int cb=0; cb<cbN; ++cb){
    const int cbi = blockIdx.y*cbN + cb;            // 64-col group 0..3
    const int colBase = cbi*64;
    const h16* wfBase = Wfrag + (size_t)cbi*8*16*512 + (size_t)l*8;

    // prologue: DMA B(kc=0)
    #pragma unroll
    for (int i=0; i<4; ++i)
      DMA16(wfBase + ((size_t)(w*4 + i))*512, &ldsB[(w*4 + i)*512]);
    __syncthreads();   // drains A-DMA (cb==0) + B(0) + prior epilogue reads

    f32x4 acc[4][2][2] = {};   // [gate f,i,o,u][rt][ct]
    #pragma unroll
    for (int kc=0; kc<8; ++kc){
      f16x8 aF[2], bF[4][2];
      #pragma unroll
      for (int rt=0; rt<2; ++rt)
        aF[rt] = *(const f16x8*)&ldsA[(((waveR*2 + rt)*8 + kc)*64 + l)*8];
      #pragma unroll
      for (int g=0; g<4; ++g)
        #pragma unroll
        for (int ct=0; ct<2; ++ct)
          bF[g][ct] = *(const f16x8*)&ldsB[((g*4 + waveC*2 + ct)*64 + l)*8];
      __syncthreads();   // all reads done
      if (kc < 7){
        #pragma unroll
        for (int i=0; i<4; ++i)
          DMA16(wfBase + ((size_t)(kc+1)*16 + w*4 + i)*512,
                &ldsB[(w*4 + i)*512]);
      }
      #pragma unroll
      for (int g=0; g<4; ++g)
        #pragma unroll
        for (int rt=0; rt<2; ++rt)
          #pragma unroll
          for (int ct=0; ct<2; ++ct)
            acc[g][rt][ct] = __builtin_amdgcn_mfma_f32_16x16x32_f16(
                aF[rt], bF[g][ct], acc[g][rt][ct], 0,0,0);
      __syncthreads();   // drains B(kc+1)
    }

    // ---- epilogue (all lane-local; sibling pairs = adjacent C regs) ----
    #pragma unroll
    for (int ct=0; ct<2; ++ct){
      const int c = colBase + waveC*32 + ct*16 + li;
      const float fb  = Ufb[c];
      const float bi_ = biou[c], bo_ = biou[256+c], bu_ = biou[512+c];
      float rsum = 0.f;
      #pragma unroll
      for (int rt=0; rt<2; ++rt){
        #pragma unroll
        for (int pp=0; pp<2; ++pp){
          const int crel = waveR*32 + rt*16 + q*4 + 2*pp;  // even child row (rel)
          const int m = bx*32 + (crel >> 1);               // global parent index
          const int rr2 = m >> log2n;
          const int jn = m & (n - 1);
          const float cl = (float)cChild[(size_t)(bx*64 + crel)*256 + c];
          const float cr = (float)cChild[(size_t)(bx*64 + crel + 1)*256 + c];
          const float fl = sigf(acc[0][rt][ct][2*pp]   + fb);
          const float fr = sigf(acc[0][rt][ct][2*pp+1] + fb);
          const float iv = acc[1][rt][ct][2*pp] + acc[1][rt][ct][2*pp+1] + bi_;
          const float ov = acc[2][rt][ct][2*pp] + acc[2][rt][ct][2*pp+1] + bo_;
          const float uv = acc[3][rt][ct][2*pp] + acc[3][rt][ct][2*pp+1] + bu_;
          const float cnew = sig_mul_tanh(iv, uv) + fl*cl + fr*cr;
          const float hnew = sig_mul_tanh(ov, cnew);
          hUpW[(((size_t)(ndOff + jn))*256 + rr2)*256 + c] = (h16)hnew;
          cPar[((size_t)m)*256 + c] = (h16)cnew;
          rsum += hnew;
        }
      }
      if (repFold) atomicAdd(&ldsRep[c], rsum);
    }
  }

  if (repFold){
    __syncthreads();
    atomicAdd(&rep[((bx*32) >> log2n)*HS + t], ldsRep[t]);
  }
}

// ------------- rep accumulation (lvl<=4 outputs, nodes 0..30 only) ----------
__global__ __launch_bounds__(256) void rep_accum(const h16* __restrict__ H,
    float* __restrict__ rep, int nrows, int chunk){
  const int r = blockIdx.y, k = threadIdx.x;
  const int n0 = blockIdx.x * chunk;
  int n1 = n0 + chunk; if (n1 > nrows) n1 = nrows;
  float s = 0.f;
  for (int nd = n0; nd < n1; ++nd)
    s += (float)H[((size_t)nd*256 + r)*HS + k];
  atomicAdd(&rep[r*HS + k], s);
}

// ------------- classifier -------------
__global__ __launch_bounds__(256) void cls_kernel(const float* __restrict__ rep,
    const float* __restrict__ clsw, const float* __restrict__ clsb,
    float* __restrict__ out){
  const int b = blockIdx.x, k = threadIdx.x;
  const float d = fabsf(rep[b*HS + k] - rep[(128+b)*HS + k]) * (1.0f/1023.0f);
  __shared__ float r0[256], r1[256];
  r0[k] = d * clsw[k];
  r1[k] = d * clsw[HS + k];
  __syncthreads();
  for (int off = 128; off > 0; off >>= 1){
    if (k < off){ r0[k] += r0[k+off]; r1[k] += r1[k+off]; }
    __syncthreads();
  }
  if (k == 0){
    out[b*2 + 0] = r0[0] + clsb[0];
    out[b*2 + 1] = r1[0] + clsb[1];
  }
}

extern "C" void kernel_launch(void* const* d_in, const int* in_sizes, int n_in,
                              void* d_out, int out_size, void* d_ws, size_t ws_size,
                              hipStream_t stream){
  const int*   types1 = (const int*)d_in[0];
  const int*   types2 = (const int*)d_in[1];
  const float* emb    = (const float*)d_in[2];
  const float* Wiou   = (const float*)d_in[3];
  const float* Uiou   = (const float*)d_in[4];
  const float* biou   = (const float*)d_in[5];
  const float* Ufw    = (const float*)d_in[6];
  const float* Ufb    = (const float*)d_in[7];
  const float* clsw   = (const float*)d_in[8];
  const float* clsb   = (const float*)d_in[9];
  float* out = (float*)d_out;

  // ---- overlay layout (h16 units). Total 116,588,544 h16 = 233.18 MB ----
  h16* ws      = (h16*)d_ws;
  // GT16 [0, 32,768,000) overlays emb16 (dead after ht_mfma);
  // hUpLow+cB overlay GT16 (dead after lvl8_cell).
  h16* GT16    = ws;                         // 32,768,000 h16 = 65.5 MB
  h16* emb16   = ws + 24576000UL;            //  8,192,000
  h16* Wx16    = ws + 32768000UL;            //    196,608 (dead after swizzle)
  h16* hUpLow  = ws;                         // 16,711,680 (nodes 0..254)
  h16* cB      = ws + 16711680UL;            //  8,388,608
  h16* hT      = ws + 65536000UL;            //  8,192,000
  h16* cT      = ws + 73728000UL;            //  8,192,000
  h16* hUpHigh = ws + 81920000UL;            // 16,777,216 (nodes 255..510 local)
  h16* cA      = ws + 98697216UL;            // 16,777,216
  h16* W16     = ws + 115474432UL;           //    262,144
  h16* Wfrag   = ws + 115736576UL;           //    524,288
  float* rep   = (float*)(ws + 116260864UL); //     65,536 f32
  h16* WxFrag  = ws + 116391936UL;           //    196,608

  convert_all<<<4224, 256, 0, stream>>>(emb, Ufw, Uiou, Wiou, emb16, W16, Wx16, rep);
  swizzle_all<<<352, 256, 0, stream>>>(W16, Wx16, Wfrag, WxFrag);
  ht_mfma<<<500, 256, 0, stream>>>(emb16, WxFrag, biou, hT, cT);
  gt16_mfma<<<500, 256, 0, stream>>>(hT, Wfrag, biou, Ufb, GT16); // overwrites emb16
  lvl8_cell<<<2048, 256, 0, stream>>>(types1, types2, GT16, cT, hT,
                                      hUpHigh, cA, rep);

  const h16* cprev = cA;
  for (int lvl = 7; lvl >= 0; --lvl){
    const int children = 512 << lvl;        // B2 * 2n
    const int cbN = (lvl >= 6) ? 4 : 1;     // big levels: y=1, col loop in-block
    h16* cout = ((8 - lvl) & 1) ? cB : cA;
    const h16* hin = (lvl == 7) ? hUpHigh : hUpLow;
    const int cOff  = (lvl == 7) ? 0 : ((1 << (lvl + 1)) - 1);
    const int ndOff = (1 << lvl) - 1;
    const int repFold = (lvl >= 5) ? 1 : 0; // rr2 block-constant iff log2n>=5
    level_mfma<<<dim3(children/64, 4/cbN), 256, 0, stream>>>(
        hin, cprev, Wfrag, biou, Ufb, hUpLow, cout, rep,
        lvl, cbN, cOff, ndOff, repFold);
    cprev = cout;
  }
  // only lvl<=4 outputs (nodes 0..30) still need scanning
  rep_accum<<<dim3(1, B2), 256, 0, stream>>>(hUpLow, rep, 31, 31);
  cls_kernel<<<128, 256, 0, stream>>>(rep, clsw, clsb, out);
}